// Round 11
// baseline (203.965 us; speedup 1.0000x reference)
//
#include <hip/hip_runtime.h>
#include <stdint.h>

#define NPTS 8192
#define KNN 32
#define KPN 15
#define SCC 64
#define OUTC 256
#define R2F 0.0144f              /* radius^2: the reference's in_range mask.
                                    NOTE: must be RADIUS^2, NOT EXTENT^2 —
                                    influence is dist(rel, kernel_pt) < EXT,
                                    and kernel points are offset from origin,
                                    so neighbors in (EXT, RADIUS] contribute. */
#define INV_EXT (1.0f/0.096f)
#define SCAP 128                 /* per-query survivor cap */
#define NT 8                     /* points per kpconv block */
#define COB 32                   /* rows per conv_out block */
#define GD 8                     /* grid dim: cell 0.125 >= RADIUS 0.12 */
#define NCELL (GD*GD*GD)         /* 512 cells per cloud */
#define KJ (KPN*SCC)             /* 960: contraction length */
#define AGP 968                  /* agg_s row stride (bf16) */

typedef float  f32x4  __attribute__((ext_vector_type(4)));
typedef __bf16 bf16x8 __attribute__((ext_vector_type(8)));

__device__ __forceinline__ int cell_of(float x) {
  int c = (int)(x * (float)GD);
  return c < 0 ? 0 : (c > GD-1 ? GD-1 : c);
}

// ---- prep: coords-copy | WkpT cvt | WinF cvt (independent, one launch) ------
// blocks 0..191: coords tail of output; 192..431: wkp_cvt; 432..495: win_cvt.
__global__ __launch_bounds__(256) void prep_k(
    const float* __restrict__ scd, const float* __restrict__ tcd,
    float* __restrict__ out,
    const float* __restrict__ Wkp, __bf16* __restrict__ WkpT,
    const float* __restrict__ Win, __bf16* __restrict__ WinF)
{
  int b = blockIdx.x, t = threadIdx.x;
  if (b < 192) {                       // coords: 49152 floats
    int i = b*256 + t;
    out[i] = (i < NPTS*3) ? scd[i] : tcd[i - NPTS*3];
  } else if (b < 432) {                // WkpT[d][j] = Wkp[j][d], bf16
    int i = (b - 192)*256 + t;         // 0..61439
    int j = i >> 6, d = i & 63;
    WkpT[(size_t)d*KJ + j] = (__bf16)Wkp[i];
  } else {                             // WinF fragment-ordered bf16 (32 KB)
    int i = (b - 432)*256 + t;         // 0..16383
    int j = i & 7, lane = (i >> 3) & 63, cc = i >> 9;
    int kc = cc >> 2, ct = cc & 3;
    int g16 = lane >> 4, p = lane & 15;
    int k = kc*32 + g16*8 + j;
    WinF[i] = (__bf16)Win[(size_t)k*64 + ct*16 + p];
  }
}

// ---- grid build: LDS histogram + scan + stats zero, ONE block ---------------
// Replaces {hist zero, grid_count, grid_scan}: histogram lives in LDS so no
// global zeroing hazard; also zeroes stats (needed before conv_out_bn).
__global__ __launch_bounds__(1024) void grid_build(
    const float* __restrict__ cA, const float* __restrict__ cB,
    unsigned int* __restrict__ starts,     // [2][520], [512] = total
    unsigned int* __restrict__ cursor,     // [2][512]
    float* __restrict__ stats)
{
  __shared__ unsigned int hcnt[2][NCELL];  // 4 KB
  __shared__ unsigned int a[NCELL], b[NCELL];
  int t = threadIdx.x;
  if (t < NCELL) { hcnt[0][t] = 0u; hcnt[1][t] = 0u; }
  stats[t] = 0.f;                          // 1024 = 2 clouds x 512
  __syncthreads();
  for (int i = t; i < 2*NPTS; i += 1024) {
    int cloud = i >> 13, n = i & 8191;
    const float* coords = cloud ? cB : cA;
    int cx = cell_of(coords[(size_t)n*3]);
    int cy = cell_of(coords[(size_t)n*3+1]);
    int cz = cell_of(coords[(size_t)n*3+2]);
    atomicAdd(&hcnt[cloud][(cz*GD + cy)*GD + cx], 1u);
  }
  __syncthreads();
  for (int cloud = 0; cloud < 2; ++cloud) {
    if (t < NCELL) a[t] = hcnt[cloud][t];
    __syncthreads();
    unsigned int *s = a, *d = b;
    for (int off = 1; off < NCELL; off <<= 1) {
      if (t < NCELL) {
        unsigned int x = s[t];
        if (t >= off) x += s[t - off];
        d[t] = x;
      }
      __syncthreads();
      unsigned int* tmp = s; s = d; d = tmp;
    }
    if (t < NCELL) {
      unsigned int inc = s[t];
      unsigned int exc = inc - hcnt[cloud][t];
      starts[cloud*520 + t] = exc;
      cursor[cloud*NCELL + t] = exc;
      if (t == NCELL-1) starts[cloud*520 + NCELL] = inc;   // = 8192
    }
    __syncthreads();
  }
}

__global__ __launch_bounds__(256) void grid_scatter(
    const float* __restrict__ cA, const float* __restrict__ cB,
    unsigned int* __restrict__ cursor, float4* __restrict__ sorted)
{
  int i = blockIdx.x*256 + threadIdx.x;   // 0..16383
  int cloud = i >> 13, n = i & 8191;
  const float* coords = cloud ? cB : cA;
  float x = coords[(size_t)n*3], y = coords[(size_t)n*3+1], z = coords[(size_t)n*3+2];
  int cell = (cell_of(z)*GD + cell_of(y))*GD + cell_of(x);
  unsigned int slot = atomicAdd(&cursor[cloud*NCELL + cell], 1u);
  sorted[(size_t)cloud*NPTS + slot] = make_float4(x, y, z, __int_as_float(n));
}

// ---- kNN (blocks 0..4095) + conv_in MFMA (blocks 4096..4351), one launch ----
// Independent producers merged to cut a dispatch; conv_in overlaps knn's tail.
__global__ __launch_bounds__(256) void knn_convin_k(
    const float* __restrict__ cA, const float* __restrict__ cB,
    const unsigned int* __restrict__ starts, const float4* __restrict__ sorted,
    short* __restrict__ fidx,
    const float* __restrict__ src, const float* __restrict__ tgt,
    const __bf16* __restrict__ WinF, const float* __restrict__ bin,
    __bf16* __restrict__ h)
{
  __shared__ unsigned long long surv[4][SCAP];   // 4 KB, wave-private rows
  int bId = blockIdx.x;
  int t = threadIdx.x, w = t >> 6, lane = t & 63;
  if (bId >= 4096) {
    // ---- conv_in: MFMA GEMM [16384x256]@[256x64], 16 rows/wave ----
    // Fragment contract (HW-verified rounds 8/9): afrag=A[m=lane&15][kslot],
    // bfrag=B[kslot][n=lane&15], D col=lane&15 row=(lane>>4)*4+r.
    int rt = (bId - 4096)*4 + w;       // row-tile 0..1023
    int row0 = rt*16;
    const float* x = (row0 >> 13) ? tgt : src;
    int n0 = row0 & 8191;
    int g16 = lane >> 4, p = lane & 15;
    const float* xrow = x + (size_t)(n0 + p)*256;
    f32x4 acc[4];
    #pragma unroll
    for (int ct = 0; ct < 4; ++ct) {
      float bb = bin[ct*16 + p];
      acc[ct] = (f32x4){bb, bb, bb, bb};
    }
    #pragma unroll
    for (int kc = 0; kc < 8; ++kc) {
      float4 xa = *(const float4*)(xrow + kc*32 + g16*8);
      float4 xb = *(const float4*)(xrow + kc*32 + g16*8 + 4);
      bf16x8 af;
      af[0]=(__bf16)xa.x; af[1]=(__bf16)xa.y; af[2]=(__bf16)xa.z; af[3]=(__bf16)xa.w;
      af[4]=(__bf16)xb.x; af[5]=(__bf16)xb.y; af[6]=(__bf16)xb.z; af[7]=(__bf16)xb.w;
      #pragma unroll
      for (int ct = 0; ct < 4; ++ct) {
        bf16x8 bf = *(const bf16x8*)(WinF + (size_t)(kc*4 + ct)*512 + lane*8);
        acc[ct] = __builtin_amdgcn_mfma_f32_16x16x32_bf16(af, bf, acc[ct], 0,0,0);
      }
    }
    #pragma unroll
    for (int ct = 0; ct < 4; ++ct)
      #pragma unroll
      for (int r = 0; r < 4; ++r)
        h[(size_t)(row0 + g16*4 + r)*SCC + ct*16 + p] = (__bf16)acc[ct][r];
    return;
  }
  // ---- kNN: spatial grid, one wave per query ----
  int q = bId*4 + w;                   // 0..16383
  int cloud = q >> 13, n = q & 8191;
  const float* coords = cloud ? cB : cA;
  float qx = coords[(size_t)n*3];
  float qy = coords[(size_t)n*3+1];
  float qz = coords[(size_t)n*3+2];
  int cx = cell_of(qx), cy = cell_of(qy), cz = cell_of(qz);
  const unsigned int* st = starts + cloud*520;
  const float4* sp = sorted + (size_t)cloud*NPTS;
  int c0 = cx > 0 ? cx-1 : 0;
  int c1 = cx < GD-1 ? cx+1 : GD-1;
  unsigned int cnt = 0;
  for (int dz = -1; dz <= 1; ++dz) {
    int zz = cz + dz; if (zz < 0 || zz > GD-1) continue;
    for (int dy = -1; dy <= 1; ++dy) {
      int yy = cy + dy; if (yy < 0 || yy > GD-1) continue;
      int rb = (zz*GD + yy)*GD;
      unsigned int s = st[rb + c0];
      unsigned int e = st[rb + c1 + 1];
      for (unsigned int jj = s; jj < e; jj += 64) {
        unsigned int j = jj + lane;
        bool keep = false; float d2 = 0.f; unsigned int oi = 0;
        if (j < e) {
          float4 p4 = sp[j];
          float dx = qx-p4.x, dyy = qy-p4.y, dzz = qz-p4.z;
          d2 = fmaf(dx, dx, fmaf(dyy, dyy, dzz*dzz));
          oi = __float_as_uint(p4.w);
          keep = (d2 <= R2F);
        }
        unsigned long long m = __ballot(keep);
        if (keep) {
          unsigned int before = __builtin_amdgcn_mbcnt_hi(
              (unsigned int)(m >> 32),
              __builtin_amdgcn_mbcnt_lo((unsigned int)m, 0u));
          unsigned int pos = cnt + before;
          if (pos < SCAP)
            surv[w][pos] = ((unsigned long long)__float_as_uint(d2) << 32) | oi;
        }
        cnt += (unsigned int)__popcll(m);
      }
    }
  }
  int C = (int)cnt; if (C > SCAP) C = SCAP;
  unsigned long long k0 = (lane      < C) ? surv[w][lane]      : ~0ULL;
  unsigned long long k1 = (lane + 64 < C) ? surv[w][lane + 64] : ~0ULL;
  int r0 = 0, r1 = 0;
  for (int j = 0; j < C; ++j) {
    unsigned long long kj = surv[w][j];      // same addr all lanes: broadcast
    r0 += (kj < k0);
    r1 += (kj < k1);
  }
  size_t g = (size_t)cloud*NPTS + n;
  if (k0 != ~0ULL && r0 < KNN) fidx[g*KNN + r0] = (short)(k0 & 0xffffu);
  if (k1 != ~0ULL && r1 < KNN) fidx[g*KNN + r1] = (short)(k1 & 0xffffu);
  if (lane >= C && lane < KNN) fidx[g*KNN + lane] = (short)-1;   // sentinels
}

// ---- fused KPConv v7: MFMA A+B, register-preloaded WkpT (T14 split) ----------
// __launch_bounds__(512,4): 128-VGPR budget (v6's 32 VGPRs starved ILP ->
// Phase B's 15 L2 loads serialized at ~200cy each). The 15 A-fragments of
// Phase B depend only on kernel args, so they are preloaded BEFORE the
// barrier: L2 latency hides under Phase A + barrier wait; Phase B is then a
// pure ds_read+MFMA chain.
__global__ __launch_bounds__(512, 4) void kpconv_fused(
    const float* __restrict__ cA, const float* __restrict__ cB,
    const float* __restrict__ kpts, const short* __restrict__ fidx,
    const __bf16* __restrict__ h, const __bf16* __restrict__ WkpT,
    float* __restrict__ h2)
{
  __shared__ __bf16 agg_s[NT][AGP];     // 15.5 KB
  __shared__ float  red2[2*4*16*17];    // 8.5 KB: [kh][dt][m][pt(17)]
  int t = threadIdx.x;
  int w = t >> 6, lane = t & 63;
  int gq = blockIdx.x*NT + w;           // 0..16383 = cloud*NPTS + n
  int cloud = gq >> 13, n = gq & 8191;
  const float* coords = cloud ? cB : cA;
  int idxreg = fidx[(size_t)gq*KNN + (lane & 31)];   // lanes 32-63 mirror 0-31
  float qx = coords[(size_t)n*3];
  float qy = coords[(size_t)n*3+1];
  float qz = coords[(size_t)n*3+2];
  int g16 = lane >> 4;                  // k-group: this lane covers k=g16*8+j
  int p   = lane & 15;                  // A-row (kernel point) and B/D column
  int pc  = p < KPN ? p : 0;            // clamp: p==15 row is zero-weighted
  float kpx = kpts[pc*3], kpy = kpts[pc*3+1], kpz = kpts[pc*3+2];
  // A-fragment: w[p][k] in bf16; remember clamped idx per j for the gather.
  bf16x8 afrag;
  int idxs[8];
  #pragma unroll
  for (int j = 0; j < 8; ++j) {
    int k = g16*8 + j;
    int idx = __shfl(idxreg, k);        // idx for neighbor k (lanes 0-31 hold)
    idxs[j] = idx < 0 ? 0 : idx;
    float wv = 0.f;
    if (idx >= 0 && p < KPN) {
      float rx = coords[(size_t)idx*3]   - qx;
      float ry = coords[(size_t)idx*3+1] - qy;
      float rz = coords[(size_t)idx*3+2] - qz;
      float dx = rx - kpx, dy = ry - kpy, dz = rz - kpz;
      float d = sqrtf(fmaf(dx, dx, fmaf(dy, dy, dz*dz)));
      wv = fmaxf(1.0f - d*INV_EXT, 0.0f);
    }
    afrag[j] = (__bf16)wv;              // idx<0 -> 0: zero A kills garbage B
  }
  // B-fragments: h[idx_k][ct*16 + p] (bf16, no cvt), 4 channel tiles.
  bf16x8 bfrag0, bfrag1, bfrag2, bfrag3;
  #pragma unroll
  for (int j = 0; j < 8; ++j) {
    const __bf16* hrow = h + ((size_t)(cloud*NPTS + idxs[j]))*SCC + p;
    bfrag0[j] = hrow[0];
    bfrag1[j] = hrow[16];
    bfrag2[j] = hrow[32];
    bfrag3[j] = hrow[48];
  }
  f32x4 acc0 = {0.f,0.f,0.f,0.f}, acc1 = acc0, acc2 = acc0, acc3 = acc0;
  acc0 = __builtin_amdgcn_mfma_f32_16x16x32_bf16(afrag, bfrag0, acc0, 0, 0, 0);
  acc1 = __builtin_amdgcn_mfma_f32_16x16x32_bf16(afrag, bfrag1, acc1, 0, 0, 0);
  acc2 = __builtin_amdgcn_mfma_f32_16x16x32_bf16(afrag, bfrag2, acc2, 0, 0, 0);
  acc3 = __builtin_amdgcn_mfma_f32_16x16x32_bf16(afrag, bfrag3, acc3, 0, 0, 0);
  // Store D -> agg_s bf16: row pp=g16*4+r, cols ct*16+p.
  #pragma unroll
  for (int r = 0; r < 4; ++r) {
    int pp = g16*4 + r;
    if (pp < KPN) {                     // pp==15 is the dummy row
      agg_s[w][pp*SCC +      p] = (__bf16)acc0[r];
      agg_s[w][pp*SCC + 16 + p] = (__bf16)acc1[r];
      agg_s[w][pp*SCC + 32 + p] = (__bf16)acc2[r];
      agg_s[w][pp*SCC + 48 + p] = (__bf16)acc3[r];
    }
  }
  // Preload Phase-B A-fragments (independent of agg_s): issue-early, the L2
  // latency hides under the barrier wait. 60 VGPRs, budget is 128.
  int dt = w & 3, kh = w >> 2;
  const __bf16* arow = WkpT + (size_t)(dt*16 + p)*KJ + kh*480 + g16*8;
  bf16x8 afB[15];
  #pragma unroll
  for (int s = 0; s < 15; ++s) afB[s] = *(const bf16x8*)(arow + s*32);
  __syncthreads();                      // publish agg_s
  // Phase B: wave = (d-tile dt, K-half kh). 15 MFMA, K=480 each half.
  {
    int ptb = p & 7;                    // B col -> point (cols 8-15 duplicate)
    const __bf16* brow = &agg_s[ptb][kh*480 + g16*8];
    f32x4 accB = {0.f,0.f,0.f,0.f};
    #pragma unroll
    for (int s = 0; s < 15; ++s) {
      bf16x8 bfr = *(const bf16x8*)(brow + s*32);
      accB = __builtin_amdgcn_mfma_f32_16x16x32_bf16(afB[s], bfr, accB, 0, 0, 0);
    }
    if (p < 8) {                        // cols 8-15 are duplicates: drop
      #pragma unroll
      for (int r = 0; r < 4; ++r)
        red2[((kh*4 + dt)*16 + g16*4 + r)*17 + p] = accB[r];
    }
  }
  __syncthreads();                      // publish red2
  {
    int pt = t >> 6, d = t & 63;        // one h2 element, coalesced store
    float v = red2[d*17 + pt] + red2[(64 + d)*17 + pt];
    h2[((size_t)blockIdx.x*NT + pt)*SCC + d] = v;
  }
}

// ---- conv_out + bias + BN partial stats: tiled GEMM, all operands in LDS -----
__global__ __launch_bounds__(512) void conv_out_bn(
    const float* __restrict__ h2, const float* __restrict__ W,
    const float* __restrict__ b, float* __restrict__ y,
    float* __restrict__ stats)
{
  __shared__ float w_s[SCC*OUTC];      // 64 KB
  __shared__ float h_s[COB][SCC];      // 8 KB
  __shared__ float rs_s[2][OUTC];      // 2 KB
  __shared__ float rs2_s[2][OUTC];     // 2 KB
  int t = threadIdx.x;
  int d = t & 255, rg = t >> 8;        // rg in {0,1}: 16-row halves
  int row0 = blockIdx.x*COB;
  int cloud = (int)(blockIdx.x >> 8);  // 256 blocks per cloud
  {
    const float4* gw = (const float4*)W;
    float4* lw = (float4*)w_s;
    #pragma unroll
    for (int i = 0; i < 8; ++i) lw[t + 512*i] = gw[t + 512*i];
    const float4* gh = (const float4*)(h2 + (size_t)row0*SCC);
    ((float4*)h_s)[t] = gh[t];
  }
  __syncthreads();
  float acc[16];
  float bb = b[d];
  #pragma unroll
  for (int r = 0; r < 16; ++r) acc[r] = bb;
  int rb = rg*16;
  #pragma unroll 4
  for (int c4 = 0; c4 < 16; ++c4) {
    float w0 = w_s[(c4*4+0)*OUTC + d];
    float w1 = w_s[(c4*4+1)*OUTC + d];
    float w2 = w_s[(c4*4+2)*OUTC + d];
    float w3 = w_s[(c4*4+3)*OUTC + d];
    #pragma unroll
    for (int r = 0; r < 16; ++r) {
      float4 hv = *(const float4*)&h_s[rb + r][c4*4];
      acc[r] = fmaf(hv.x,w0, fmaf(hv.y,w1, fmaf(hv.z,w2, fmaf(hv.w,w3, acc[r]))));
    }
  }
  float s = 0.f, s2 = 0.f;
  #pragma unroll
  for (int r = 0; r < 16; ++r) {
    float v = acc[r];
    y[((size_t)row0 + rb + r)*OUTC + d] = v;
    s += v; s2 = fmaf(v, v, s2);
  }
  rs_s[rg][d] = s; rs2_s[rg][d] = s2;
  __syncthreads();
  if (rg == 0) {
    atomicAdd(&stats[cloud*512 + d],       s  + rs_s[1][d]);
    atomicAdd(&stats[cloud*512 + 256 + d], s2 + rs2_s[1][d]);
  }
}

// ---- BN apply ----------------------------------------------------------------
__global__ __launch_bounds__(256) void bn_apply_k(
    float* __restrict__ y, const float* __restrict__ stats,
    const float* __restrict__ gamma, const float* __restrict__ beta)
{
  size_t e = (size_t)blockIdx.x*256 + threadIdx.x;
  int c = (int)(e & 255);
  int cloud = (int)(e >> 21);
  float s  = stats[cloud*512 + c];
  float s2 = stats[cloud*512 + 256 + c];
  float mu  = s * (1.0f/NPTS);
  float var = fmaxf(s2 * (1.0f/NPTS) - mu*mu, 0.f);
  float sc = gamma[c] * rsqrtf(var + 1e-5f);
  float sh = beta[c] - mu*sc;
  float v = fmaf(y[e], sc, sh);
  v = v > 0.f ? v : 0.1f*v;
  y[e] = v;
}

extern "C" void kernel_launch(void* const* d_in, const int* in_sizes, int n_in,
                              void* d_out, int out_size, void* d_ws, size_t ws_size,
                              hipStream_t stream)
{
  (void)in_sizes; (void)n_in; (void)out_size; (void)ws_size;
  const float* src   = (const float*)d_in[0];
  const float* tgt   = (const float*)d_in[1];
  const float* scd   = (const float*)d_in[2];
  const float* tcd   = (const float*)d_in[3];
  const float* W_in  = (const float*)d_in[4];
  const float* b_in  = (const float*)d_in[5];
  const float* kpts  = (const float*)d_in[6];
  const float* W_kp  = (const float*)d_in[7];
  const float* W_out = (const float*)d_in[8];
  const float* b_out = (const float*)d_in[9];
  const float* gamma = (const float*)d_in[10];
  const float* beta  = (const float*)d_in[11];

  // ---- workspace ----
  char* ws = (char*)d_ws;
  __bf16* h    = (__bf16*)ws;                       // 0..2 MB  [2][8192][64] bf16
  float* h2    = (float*)(ws + (4u<<20));           // 4..8 MB  [2][8192][64] f32
  short* fidx  = (short*)(ws + (8u<<20));           // 8..9 MB [16384][32] i16
  float* stats = (float*)(ws + (9u<<20));           // 4 KB
  __bf16* WkpT = (__bf16*)(ws + (9u<<20) + (64u<<10));  // 120 KB [64][960] bf16
  __bf16* WinF = (__bf16*)(ws + (9u<<20) + (256u<<10)); // 32 KB fragment-ordered
  // grid aux lives INSIDE the h2 region: dead before kpconv's first h2 write
  unsigned int* starts = (unsigned int*)(ws + (4u<<20) + (8u<<10)); // 2x520 u32
  unsigned int* cursor = (unsigned int*)(ws + (4u<<20) + (16u<<10));// 4 KB
  float4* sorted       = (float4*)(ws + (4u<<20) + (32u<<10));      // 256 KB

  float* yout = (float*)d_out;

  prep_k<<<496, 256, 0, stream>>>(scd, tcd, yout + (size_t)2*NPTS*OUTC,
                                  W_kp, WkpT, W_in, WinF);
  grid_build<<<1, 1024, 0, stream>>>(scd, tcd, starts, cursor, stats);
  grid_scatter<<<64, 256, 0, stream>>>(scd, tcd, cursor, sorted);
  knn_convin_k<<<4352, 256, 0, stream>>>(scd, tcd, starts, sorted, fidx,
                                         src, tgt, WinF, b_in, h);
  kpconv_fused<<<2048, 512, 0, stream>>>(scd, tcd, kpts, fidx, h, WkpT, h2);
  conv_out_bn<<<512, 512, 0, stream>>>(h2, W_out, b_out, yout, stats);
  bn_apply_k<<<16384, 256, 0, stream>>>(yout, stats, gamma, beta);
}

// Round 12
// 202.882 us; speedup vs baseline: 1.0053x; 1.0053x over previous
//
#include <hip/hip_runtime.h>
#include <stdint.h>

#define NPTS 8192
#define KNN 32
#define KPN 15
#define SCC 64
#define OUTC 256
#define R2F 0.0144f              /* radius^2: the reference's in_range mask.
                                    NOTE: must be RADIUS^2, NOT EXTENT^2 —
                                    influence is dist(rel, kernel_pt) < EXT,
                                    and kernel points are offset from origin,
                                    so neighbors in (EXT, RADIUS] contribute. */
#define INV_EXT (1.0f/0.096f)
#define SCAP 128                 /* per-query survivor cap */
#define NT 8                     /* points per kpconv block */
#define COB 32                   /* rows per conv_out block */
#define GD 8                     /* grid dim: cell 0.125 >= RADIUS 0.12 */
#define NCELL (GD*GD*GD)         /* 512 cells per cloud */
#define KJ (KPN*SCC)             /* 960: contraction length */
#define AGP 968                  /* agg_s row stride (bf16) */

typedef float  f32x4  __attribute__((ext_vector_type(4)));
typedef __bf16 bf16x8 __attribute__((ext_vector_type(8)));
typedef __bf16 bf16x4 __attribute__((ext_vector_type(4)));

__device__ __forceinline__ int cell_of(float x) {
  int c = (int)(x * (float)GD);
  return c < 0 ? 0 : (c > GD-1 ? GD-1 : c);
}

// ---- prep: coords-copy | WkpT cvt | WinF cvt (independent, one launch) ------
__global__ __launch_bounds__(256) void prep_k(
    const float* __restrict__ scd, const float* __restrict__ tcd,
    float* __restrict__ out,
    const float* __restrict__ Wkp, __bf16* __restrict__ WkpT,
    const float* __restrict__ Win, __bf16* __restrict__ WinF)
{
  int b = blockIdx.x, t = threadIdx.x;
  if (b < 192) {                       // coords: 49152 floats
    int i = b*256 + t;
    out[i] = (i < NPTS*3) ? scd[i] : tcd[i - NPTS*3];
  } else if (b < 432) {                // WkpT[d][j] = Wkp[j][d], bf16
    int i = (b - 192)*256 + t;         // 0..61439
    int j = i >> 6, d = i & 63;
    WkpT[(size_t)d*KJ + j] = (__bf16)Wkp[i];
  } else {                             // WinF fragment-ordered bf16 (32 KB)
    int i = (b - 432)*256 + t;         // 0..16383
    int j = i & 7, lane = (i >> 3) & 63, cc = i >> 9;
    int kc = cc >> 2, ct = cc & 3;
    int g16 = lane >> 4, p = lane & 15;
    int k = kc*32 + g16*8 + j;
    WinF[i] = (__bf16)Win[(size_t)k*64 + ct*16 + p];
  }
}

// ---- grid build: LDS histogram + scan + stats zero, ONE block ---------------
__global__ __launch_bounds__(1024) void grid_build(
    const float* __restrict__ cA, const float* __restrict__ cB,
    unsigned int* __restrict__ starts,     // [2][520], [512] = total
    unsigned int* __restrict__ cursor,     // [2][512]
    float* __restrict__ stats)
{
  __shared__ unsigned int hcnt[2][NCELL];  // 4 KB
  __shared__ unsigned int a[NCELL], b[NCELL];
  int t = threadIdx.x;
  if (t < NCELL) { hcnt[0][t] = 0u; hcnt[1][t] = 0u; }
  stats[t] = 0.f;                          // 1024 = 2 clouds x 512
  __syncthreads();
  for (int i = t; i < 2*NPTS; i += 1024) {
    int cloud = i >> 13, n = i & 8191;
    const float* coords = cloud ? cB : cA;
    int cx = cell_of(coords[(size_t)n*3]);
    int cy = cell_of(coords[(size_t)n*3+1]);
    int cz = cell_of(coords[(size_t)n*3+2]);
    atomicAdd(&hcnt[cloud][(cz*GD + cy)*GD + cx], 1u);
  }
  __syncthreads();
  for (int cloud = 0; cloud < 2; ++cloud) {
    if (t < NCELL) a[t] = hcnt[cloud][t];
    __syncthreads();
    unsigned int *s = a, *d = b;
    for (int off = 1; off < NCELL; off <<= 1) {
      if (t < NCELL) {
        unsigned int x = s[t];
        if (t >= off) x += s[t - off];
        d[t] = x;
      }
      __syncthreads();
      unsigned int* tmp = s; s = d; d = tmp;
    }
    if (t < NCELL) {
      unsigned int inc = s[t];
      unsigned int exc = inc - hcnt[cloud][t];
      starts[cloud*520 + t] = exc;
      cursor[cloud*NCELL + t] = exc;
      if (t == NCELL-1) starts[cloud*520 + NCELL] = inc;   // = 8192
    }
    __syncthreads();
  }
}

// ---- scatter: cell-sorted float4 + dense coords4 gather table ---------------
__global__ __launch_bounds__(256) void grid_scatter(
    const float* __restrict__ cA, const float* __restrict__ cB,
    unsigned int* __restrict__ cursor, float4* __restrict__ sorted,
    float4* __restrict__ coords4)
{
  int i = blockIdx.x*256 + threadIdx.x;   // 0..16383
  int cloud = i >> 13, n = i & 8191;
  const float* coords = cloud ? cB : cA;
  float x = coords[(size_t)n*3], y = coords[(size_t)n*3+1], z = coords[(size_t)n*3+2];
  coords4[(size_t)cloud*NPTS + n] = make_float4(x, y, z, 0.f);
  int cell = (cell_of(z)*GD + cell_of(y))*GD + cell_of(x);
  unsigned int slot = atomicAdd(&cursor[cloud*NCELL + cell], 1u);
  sorted[(size_t)cloud*NPTS + slot] = make_float4(x, y, z, __int_as_float(n));
}

// ---- conv_in MFMA (blocks 0..255, FIRST: HBM loads overlap knn) + kNN -------
__global__ __launch_bounds__(256) void knn_convin_k(
    const float4* __restrict__ coords4,
    const unsigned int* __restrict__ starts, const float4* __restrict__ sorted,
    short* __restrict__ fidx,
    const float* __restrict__ src, const float* __restrict__ tgt,
    const __bf16* __restrict__ WinF, const float* __restrict__ bin,
    __bf16* __restrict__ h)
{
  __shared__ unsigned long long surv[4][SCAP];   // 4 KB, wave-private rows
  int bId = blockIdx.x;
  int t = threadIdx.x, w = t >> 6, lane = t & 63;
  if (bId < 256) {
    // ---- conv_in: MFMA GEMM [16384x256]@[256x64], 16 rows/wave ----
    // afrag=A[m=lane&15][kslot], bfrag=B[kslot][n=lane&15],
    // D col=lane&15 row=(lane>>4)*4+r (HW-verified). Output in hP layout:
    // hP[n][p*4+ct] = h[n][ct*16+p] -> one b64 store per row.
    int rt = bId*4 + w;                // row-tile 0..1023
    int row0 = rt*16;
    const float* x = (row0 >> 13) ? tgt : src;
    int n0 = row0 & 8191;
    int g16 = lane >> 4, p = lane & 15;
    const float* xrow = x + (size_t)(n0 + p)*256;
    f32x4 acc[4];
    #pragma unroll
    for (int ct = 0; ct < 4; ++ct) {
      float bb = bin[ct*16 + p];
      acc[ct] = (f32x4){bb, bb, bb, bb};
    }
    #pragma unroll
    for (int kc = 0; kc < 8; ++kc) {
      float4 xa = *(const float4*)(xrow + kc*32 + g16*8);
      float4 xb = *(const float4*)(xrow + kc*32 + g16*8 + 4);
      bf16x8 af;
      af[0]=(__bf16)xa.x; af[1]=(__bf16)xa.y; af[2]=(__bf16)xa.z; af[3]=(__bf16)xa.w;
      af[4]=(__bf16)xb.x; af[5]=(__bf16)xb.y; af[6]=(__bf16)xb.z; af[7]=(__bf16)xb.w;
      #pragma unroll
      for (int ct = 0; ct < 4; ++ct) {
        bf16x8 bf = *(const bf16x8*)(WinF + (size_t)(kc*4 + ct)*512 + lane*8);
        acc[ct] = __builtin_amdgcn_mfma_f32_16x16x32_bf16(af, bf, acc[ct], 0,0,0);
      }
    }
    #pragma unroll
    for (int r = 0; r < 4; ++r) {
      bf16x4 o;
      o[0] = (__bf16)acc[0][r]; o[1] = (__bf16)acc[1][r];
      o[2] = (__bf16)acc[2][r]; o[3] = (__bf16)acc[3][r];
      *(bf16x4*)(h + (size_t)(row0 + g16*4 + r)*SCC + p*4) = o;
    }
    return;
  }
  // ---- kNN: spatial grid, one wave per query ----
  int q = (bId - 256)*4 + w;           // 0..16383
  int cloud = q >> 13, n = q & 8191;
  float4 qc = coords4[(size_t)cloud*NPTS + n];
  float qx = qc.x, qy = qc.y, qz = qc.z;
  int cx = cell_of(qx), cy = cell_of(qy), cz = cell_of(qz);
  const unsigned int* st = starts + cloud*520;
  const float4* sp = sorted + (size_t)cloud*NPTS;
  int c0 = cx > 0 ? cx-1 : 0;
  int c1 = cx < GD-1 ? cx+1 : GD-1;
  unsigned int cnt = 0;
  for (int dz = -1; dz <= 1; ++dz) {
    int zz = cz + dz; if (zz < 0 || zz > GD-1) continue;
    for (int dy = -1; dy <= 1; ++dy) {
      int yy = cy + dy; if (yy < 0 || yy > GD-1) continue;
      int rb = (zz*GD + yy)*GD;
      unsigned int s = st[rb + c0];
      unsigned int e = st[rb + c1 + 1];
      for (unsigned int jj = s; jj < e; jj += 64) {
        unsigned int j = jj + lane;
        bool keep = false; float d2 = 0.f; unsigned int oi = 0;
        if (j < e) {
          float4 p4 = sp[j];
          float dx = qx-p4.x, dyy = qy-p4.y, dzz = qz-p4.z;
          d2 = fmaf(dx, dx, fmaf(dyy, dyy, dzz*dzz));
          oi = __float_as_uint(p4.w);
          keep = (d2 <= R2F);
        }
        unsigned long long m = __ballot(keep);
        if (keep) {
          unsigned int before = __builtin_amdgcn_mbcnt_hi(
              (unsigned int)(m >> 32),
              __builtin_amdgcn_mbcnt_lo((unsigned int)m, 0u));
          unsigned int pos = cnt + before;
          if (pos < SCAP)
            surv[w][pos] = ((unsigned long long)__float_as_uint(d2) << 32) | oi;
        }
        cnt += (unsigned int)__popcll(m);
      }
    }
  }
  int C = (int)cnt; if (C > SCAP) C = SCAP;
  unsigned long long k0 = (lane      < C) ? surv[w][lane]      : ~0ULL;
  unsigned long long k1 = (lane + 64 < C) ? surv[w][lane + 64] : ~0ULL;
  int r0 = 0, r1 = 0;
  for (int j = 0; j < C; ++j) {
    unsigned long long kj = surv[w][j];      // same addr all lanes: broadcast
    r0 += (kj < k0);
    r1 += (kj < k1);
  }
  size_t g = (size_t)cloud*NPTS + n;
  if (k0 != ~0ULL && r0 < KNN) fidx[g*KNN + r0] = (short)(k0 & 0xffffu);
  if (k1 != ~0ULL && r1 < KNN) fidx[g*KNN + r1] = (short)(k1 & 0xffffu);
  if (lane >= C && lane < KNN) fidx[g*KNN + lane] = (short)-1;   // sentinels
}

// ---- fused KPConv v8: MFMA A+B, wide gathers (hP b64 + coords4 b128) ---------
// v7's (512,4)+preload regressed (compiler sank the loads; occupancy cost
// only) -> reverted to plain bounds. This round attacks the real consumer:
// 56 tiny VMEM gathers/wave (32x 2B h + 24 scalar coords) -> 17 wide ones
// (8x b64 hP + 9x b128 coords4). hP[n][p*4+ct] is a pure column permutation:
// fragment values identical; conv_in writes the same permutation.
__global__ __launch_bounds__(512) void kpconv_fused(
    const float4* __restrict__ coords4,
    const float* __restrict__ kpts, const short* __restrict__ fidx,
    const __bf16* __restrict__ h, const __bf16* __restrict__ WkpT,
    float* __restrict__ h2)
{
  __shared__ __bf16 agg_s[NT][AGP];     // 15.5 KB
  __shared__ float  red2[2*4*16*17];    // 8.5 KB: [kh][dt][m][pt(17)]
  int t = threadIdx.x;
  int w = t >> 6, lane = t & 63;
  int gq = blockIdx.x*NT + w;           // 0..16383 = cloud*NPTS + n
  int cloud = gq >> 13, n = gq & 8191;
  const float4* c4 = coords4 + (size_t)cloud*NPTS;
  int idxreg = fidx[(size_t)gq*KNN + (lane & 31)];   // lanes 32-63 mirror 0-31
  float4 qc = c4[n];
  float qx = qc.x, qy = qc.y, qz = qc.z;
  int g16 = lane >> 4;                  // k-group: this lane covers k=g16*8+j
  int p   = lane & 15;                  // A-row (kernel point) and B/D column
  int pc  = p < KPN ? p : 0;            // clamp: p==15 row is zero-weighted
  float kpx = kpts[pc*3], kpy = kpts[pc*3+1], kpz = kpts[pc*3+2];
  // A-fragment: w[p][k] in bf16; remember clamped idx per j for the gather.
  bf16x8 afrag;
  int idxs[8];
  #pragma unroll
  for (int j = 0; j < 8; ++j) {
    int k = g16*8 + j;
    int idx = __shfl(idxreg, k);        // idx for neighbor k (lanes 0-31 hold)
    idxs[j] = idx < 0 ? 0 : idx;
    float4 nc = c4[idxs[j]];            // one b128 gather (clamped-safe)
    float wv = 0.f;
    if (idx >= 0 && p < KPN) {
      float dx = (nc.x - qx) - kpx;
      float dy = (nc.y - qy) - kpy;
      float dz = (nc.z - qz) - kpz;
      float d = sqrtf(fmaf(dx, dx, fmaf(dy, dy, dz*dz)));
      wv = fmaxf(1.0f - d*INV_EXT, 0.0f);
    }
    afrag[j] = (__bf16)wv;              // idx<0 -> 0: zero A kills garbage B
  }
  // B-fragments: hP[idx_k][p*4+ct] -> one b64 gather yields all 4 tiles.
  bf16x8 bfrag0, bfrag1, bfrag2, bfrag3;
  #pragma unroll
  for (int j = 0; j < 8; ++j) {
    bf16x4 hv = *(const bf16x4*)(h + ((size_t)(cloud*NPTS + idxs[j]))*SCC + p*4);
    bfrag0[j] = hv[0];
    bfrag1[j] = hv[1];
    bfrag2[j] = hv[2];
    bfrag3[j] = hv[3];
  }
  f32x4 acc0 = {0.f,0.f,0.f,0.f}, acc1 = acc0, acc2 = acc0, acc3 = acc0;
  acc0 = __builtin_amdgcn_mfma_f32_16x16x32_bf16(afrag, bfrag0, acc0, 0, 0, 0);
  acc1 = __builtin_amdgcn_mfma_f32_16x16x32_bf16(afrag, bfrag1, acc1, 0, 0, 0);
  acc2 = __builtin_amdgcn_mfma_f32_16x16x32_bf16(afrag, bfrag2, acc2, 0, 0, 0);
  acc3 = __builtin_amdgcn_mfma_f32_16x16x32_bf16(afrag, bfrag3, acc3, 0, 0, 0);
  // Store D -> agg_s bf16: row pp=g16*4+r, cols ct*16+p.
  #pragma unroll
  for (int r = 0; r < 4; ++r) {
    int pp = g16*4 + r;
    if (pp < KPN) {                     // pp==15 is the dummy row
      agg_s[w][pp*SCC +      p] = (__bf16)acc0[r];
      agg_s[w][pp*SCC + 16 + p] = (__bf16)acc1[r];
      agg_s[w][pp*SCC + 32 + p] = (__bf16)acc2[r];
      agg_s[w][pp*SCC + 48 + p] = (__bf16)acc3[r];
    }
  }
  __syncthreads();                      // publish agg_s
  // Phase B: wave = (d-tile dt, K-half kh). 15 MFMA, K=480 each half.
  {
    int dt = w & 3, kh = w >> 2;
    int ptb = p & 7;                    // B col -> point (cols 8-15 duplicate)
    const __bf16* arow = WkpT + (size_t)(dt*16 + p)*KJ + kh*480 + g16*8;
    const __bf16* brow = &agg_s[ptb][kh*480 + g16*8];
    f32x4 accB = {0.f,0.f,0.f,0.f};
    #pragma unroll
    for (int s = 0; s < 15; ++s) {
      bf16x8 af = *(const bf16x8*)(arow + s*32);
      bf16x8 bfr = *(const bf16x8*)(brow + s*32);
      accB = __builtin_amdgcn_mfma_f32_16x16x32_bf16(af, bfr, accB, 0, 0, 0);
    }
    if (p < 8) {                        // cols 8-15 are duplicates: drop
      #pragma unroll
      for (int r = 0; r < 4; ++r)
        red2[((kh*4 + dt)*16 + g16*4 + r)*17 + p] = accB[r];
    }
  }
  __syncthreads();                      // publish red2
  {
    int pt = t >> 6, d = t & 63;        // one h2 element, coalesced store
    float v = red2[d*17 + pt] + red2[(64 + d)*17 + pt];
    h2[((size_t)blockIdx.x*NT + pt)*SCC + d] = v;
  }
}

// ---- conv_out + bias + BN partial stats: tiled GEMM, all operands in LDS -----
__global__ __launch_bounds__(512) void conv_out_bn(
    const float* __restrict__ h2, const float* __restrict__ W,
    const float* __restrict__ b, float* __restrict__ y,
    float* __restrict__ stats)
{
  __shared__ float w_s[SCC*OUTC];      // 64 KB
  __shared__ float h_s[COB][SCC];      // 8 KB
  __shared__ float rs_s[2][OUTC];      // 2 KB
  __shared__ float rs2_s[2][OUTC];     // 2 KB
  int t = threadIdx.x;
  int d = t & 255, rg = t >> 8;        // rg in {0,1}: 16-row halves
  int row0 = blockIdx.x*COB;
  int cloud = (int)(blockIdx.x >> 8);  // 256 blocks per cloud
  {
    const float4* gw = (const float4*)W;
    float4* lw = (float4*)w_s;
    #pragma unroll
    for (int i = 0; i < 8; ++i) lw[t + 512*i] = gw[t + 512*i];
    const float4* gh = (const float4*)(h2 + (size_t)row0*SCC);
    ((float4*)h_s)[t] = gh[t];
  }
  __syncthreads();
  float acc[16];
  float bb = b[d];
  #pragma unroll
  for (int r = 0; r < 16; ++r) acc[r] = bb;
  int rb = rg*16;
  #pragma unroll 4
  for (int c4 = 0; c4 < 16; ++c4) {
    float w0 = w_s[(c4*4+0)*OUTC + d];
    float w1 = w_s[(c4*4+1)*OUTC + d];
    float w2 = w_s[(c4*4+2)*OUTC + d];
    float w3 = w_s[(c4*4+3)*OUTC + d];
    #pragma unroll
    for (int r = 0; r < 16; ++r) {
      float4 hv = *(const float4*)&h_s[rb + r][c4*4];
      acc[r] = fmaf(hv.x,w0, fmaf(hv.y,w1, fmaf(hv.z,w2, fmaf(hv.w,w3, acc[r]))));
    }
  }
  float s = 0.f, s2 = 0.f;
  #pragma unroll
  for (int r = 0; r < 16; ++r) {
    float v = acc[r];
    y[((size_t)row0 + rb + r)*OUTC + d] = v;
    s += v; s2 = fmaf(v, v, s2);
  }
  rs_s[rg][d] = s; rs2_s[rg][d] = s2;
  __syncthreads();
  if (rg == 0) {
    atomicAdd(&stats[cloud*512 + d],       s  + rs_s[1][d]);
    atomicAdd(&stats[cloud*512 + 256 + d], s2 + rs2_s[1][d]);
  }
}

// ---- BN apply ----------------------------------------------------------------
__global__ __launch_bounds__(256) void bn_apply_k(
    float* __restrict__ y, const float* __restrict__ stats,
    const float* __restrict__ gamma, const float* __restrict__ beta)
{
  size_t e = (size_t)blockIdx.x*256 + threadIdx.x;
  int c = (int)(e & 255);
  int cloud = (int)(e >> 21);
  float s  = stats[cloud*512 + c];
  float s2 = stats[cloud*512 + 256 + c];
  float mu  = s * (1.0f/NPTS);
  float var = fmaxf(s2 * (1.0f/NPTS) - mu*mu, 0.f);
  float sc = gamma[c] * rsqrtf(var + 1e-5f);
  float sh = beta[c] - mu*sc;
  float v = fmaf(y[e], sc, sh);
  v = v > 0.f ? v : 0.1f*v;
  y[e] = v;
}

extern "C" void kernel_launch(void* const* d_in, const int* in_sizes, int n_in,
                              void* d_out, int out_size, void* d_ws, size_t ws_size,
                              hipStream_t stream)
{
  (void)in_sizes; (void)n_in; (void)out_size; (void)ws_size;
  const float* src   = (const float*)d_in[0];
  const float* tgt   = (const float*)d_in[1];
  const float* scd   = (const float*)d_in[2];
  const float* tcd   = (const float*)d_in[3];
  const float* W_in  = (const float*)d_in[4];
  const float* b_in  = (const float*)d_in[5];
  const float* kpts  = (const float*)d_in[6];
  const float* W_kp  = (const float*)d_in[7];
  const float* W_out = (const float*)d_in[8];
  const float* b_out = (const float*)d_in[9];
  const float* gamma = (const float*)d_in[10];
  const float* beta  = (const float*)d_in[11];

  // ---- workspace ----
  char* ws = (char*)d_ws;
  __bf16* h    = (__bf16*)ws;                       // 0..2 MB  hP[2*8192][64] bf16
  float* h2    = (float*)(ws + (4u<<20));           // 4..8 MB  [2][8192][64] f32
  short* fidx  = (short*)(ws + (8u<<20));           // 8..9 MB [16384][32] i16
  float* stats = (float*)(ws + (9u<<20));           // 4 KB
  __bf16* WkpT = (__bf16*)(ws + (9u<<20) + (64u<<10));   // 120 KB [64][960] bf16
  __bf16* WinF = (__bf16*)(ws + (9u<<20) + (256u<<10));  // 32 KB fragment-ordered
  float4* coords4 = (float4*)(ws + (9u<<20) + (512u<<10)); // 256 KB [2][8192] xyz_
  // grid aux lives INSIDE the h2 region: dead before kpconv's first h2 write
  unsigned int* starts = (unsigned int*)(ws + (4u<<20) + (8u<<10)); // 2x520 u32
  unsigned int* cursor = (unsigned int*)(ws + (4u<<20) + (16u<<10));// 4 KB
  float4* sorted       = (float4*)(ws + (4u<<20) + (32u<<10));      // 256 KB

  float* yout = (float*)d_out;

  prep_k<<<496, 256, 0, stream>>>(scd, tcd, yout + (size_t)2*NPTS*OUTC,
                                  W_kp, WkpT, W_in, WinF);
  grid_build<<<1, 1024, 0, stream>>>(scd, tcd, starts, cursor, stats);
  grid_scatter<<<64, 256, 0, stream>>>(scd, tcd, cursor, sorted, coords4);
  knn_convin_k<<<4352, 256, 0, stream>>>(coords4, starts, sorted, fidx,
                                         src, tgt, WinF, b_in, h);
  kpconv_fused<<<2048, 512, 0, stream>>>(coords4, kpts, fidx, h, WkpT, h2);
  conv_out_bn<<<512, 512, 0, stream>>>(h2, W_out, b_out, yout, stats);
  bn_apply_k<<<16384, 256, 0, stream>>>(yout, stats, gamma, beta);
}

// Round 13
// 195.853 us; speedup vs baseline: 1.0414x; 1.0359x over previous
//
#include <hip/hip_runtime.h>
#include <stdint.h>

#define NPTS 8192
#define KNN 32
#define KPN 15
#define SCC 64
#define OUTC 256
#define R2F 0.0144f              /* radius^2: the reference's in_range mask.
                                    NOTE: must be RADIUS^2, NOT EXTENT^2 —
                                    influence is dist(rel, kernel_pt) < EXT,
                                    and kernel points are offset from origin,
                                    so neighbors in (EXT, RADIUS] contribute. */
#define INV_EXT (1.0f/0.096f)
#define SCAP 128                 /* per-query survivor cap */
#define COB 32                   /* rows per conv_out block */
#define GD 8                     /* grid dim: cell 0.125 >= RADIUS 0.12 */
#define NCELL (GD*GD*GD)         /* 512 cells per cloud */
#define KJ (KPN*SCC)             /* 960: contraction length */
#define AGP2 1000                /* agg_s row stride (bf16): 2000B = 500 dw,
                                    500%32=20 -> p-stride 4(5p+g16) spreads
                                    all bank groups on b128 reads */

typedef float  f32x4  __attribute__((ext_vector_type(4)));
typedef __bf16 bf16x8 __attribute__((ext_vector_type(8)));
typedef __bf16 bf16x4 __attribute__((ext_vector_type(4)));

__device__ __forceinline__ int cell_of(float x) {
  int c = (int)(x * (float)GD);
  return c < 0 ? 0 : (c > GD-1 ? GD-1 : c);
}

// ---- prep: coords-copy | WkpT cvt | WinF cvt (independent, one launch) ------
__global__ __launch_bounds__(256) void prep_k(
    const float* __restrict__ scd, const float* __restrict__ tcd,
    float* __restrict__ out,
    const float* __restrict__ Wkp, __bf16* __restrict__ WkpT,
    const float* __restrict__ Win, __bf16* __restrict__ WinF)
{
  int b = blockIdx.x, t = threadIdx.x;
  if (b < 192) {                       // coords: 49152 floats
    int i = b*256 + t;
    out[i] = (i < NPTS*3) ? scd[i] : tcd[i - NPTS*3];
  } else if (b < 432) {                // WkpT[d][j] = Wkp[j][d], bf16
    int i = (b - 192)*256 + t;         // 0..61439
    int j = i >> 6, d = i & 63;
    WkpT[(size_t)d*KJ + j] = (__bf16)Wkp[i];
  } else {                             // WinF fragment-ordered bf16 (32 KB)
    int i = (b - 432)*256 + t;         // 0..16383
    int j = i & 7, lane = (i >> 3) & 63, cc = i >> 9;
    int kc = cc >> 2, ct = cc & 3;
    int g16 = lane >> 4, p = lane & 15;
    int k = kc*32 + g16*8 + j;
    WinF[i] = (__bf16)Win[(size_t)k*64 + ct*16 + p];
  }
}

// ---- grid build: LDS histogram + scan + stats zero, ONE block ---------------
__global__ __launch_bounds__(1024) void grid_build(
    const float* __restrict__ cA, const float* __restrict__ cB,
    unsigned int* __restrict__ starts,     // [2][520], [512] = total
    unsigned int* __restrict__ cursor,     // [2][512]
    float* __restrict__ stats)
{
  __shared__ unsigned int hcnt[2][NCELL];  // 4 KB
  __shared__ unsigned int a[NCELL], b[NCELL];
  int t = threadIdx.x;
  if (t < NCELL) { hcnt[0][t] = 0u; hcnt[1][t] = 0u; }
  stats[t] = 0.f;                          // 1024 = 2 clouds x 512
  __syncthreads();
  for (int i = t; i < 2*NPTS; i += 1024) {
    int cloud = i >> 13, n = i & 8191;
    const float* coords = cloud ? cB : cA;
    int cx = cell_of(coords[(size_t)n*3]);
    int cy = cell_of(coords[(size_t)n*3+1]);
    int cz = cell_of(coords[(size_t)n*3+2]);
    atomicAdd(&hcnt[cloud][(cz*GD + cy)*GD + cx], 1u);
  }
  __syncthreads();
  for (int cloud = 0; cloud < 2; ++cloud) {
    if (t < NCELL) a[t] = hcnt[cloud][t];
    __syncthreads();
    unsigned int *s = a, *d = b;
    for (int off = 1; off < NCELL; off <<= 1) {
      if (t < NCELL) {
        unsigned int x = s[t];
        if (t >= off) x += s[t - off];
        d[t] = x;
      }
      __syncthreads();
      unsigned int* tmp = s; s = d; d = tmp;
    }
    if (t < NCELL) {
      unsigned int inc = s[t];
      unsigned int exc = inc - hcnt[cloud][t];
      starts[cloud*520 + t] = exc;
      cursor[cloud*NCELL + t] = exc;
      if (t == NCELL-1) starts[cloud*520 + NCELL] = inc;   // = 8192
    }
    __syncthreads();
  }
}

// ---- scatter: cell-sorted float4 + dense coords4 gather table ---------------
__global__ __launch_bounds__(256) void grid_scatter(
    const float* __restrict__ cA, const float* __restrict__ cB,
    unsigned int* __restrict__ cursor, float4* __restrict__ sorted,
    float4* __restrict__ coords4)
{
  int i = blockIdx.x*256 + threadIdx.x;   // 0..16383
  int cloud = i >> 13, n = i & 8191;
  const float* coords = cloud ? cB : cA;
  float x = coords[(size_t)n*3], y = coords[(size_t)n*3+1], z = coords[(size_t)n*3+2];
  coords4[(size_t)cloud*NPTS + n] = make_float4(x, y, z, 0.f);
  int cell = (cell_of(z)*GD + cell_of(y))*GD + cell_of(x);
  unsigned int slot = atomicAdd(&cursor[cloud*NCELL + cell], 1u);
  sorted[(size_t)cloud*NPTS + slot] = make_float4(x, y, z, __int_as_float(n));
}

// ---- conv_in MFMA (blocks 0..255, FIRST: HBM loads overlap knn) + kNN -------
__global__ __launch_bounds__(256) void knn_convin_k(
    const float4* __restrict__ coords4,
    const unsigned int* __restrict__ starts, const float4* __restrict__ sorted,
    short* __restrict__ fidx,
    const float* __restrict__ src, const float* __restrict__ tgt,
    const __bf16* __restrict__ WinF, const float* __restrict__ bin,
    __bf16* __restrict__ h)
{
  __shared__ unsigned long long surv[4][SCAP];   // 4 KB, wave-private rows
  int bId = blockIdx.x;
  int t = threadIdx.x, w = t >> 6, lane = t & 63;
  if (bId < 256) {
    // ---- conv_in: MFMA GEMM [16384x256]@[256x64], 16 rows/wave ----
    // afrag=A[m=lane&15][kslot], bfrag=B[kslot][n=lane&15],
    // D col=lane&15 row=(lane>>4)*4+r (HW-verified). hP output layout:
    // hP[n][p*4+ct] = h[n][ct*16+p] -> one b64 store per row.
    int rt = bId*4 + w;                // row-tile 0..1023
    int row0 = rt*16;
    const float* x = (row0 >> 13) ? tgt : src;
    int n0 = row0 & 8191;
    int g16 = lane >> 4, p = lane & 15;
    const float* xrow = x + (size_t)(n0 + p)*256;
    f32x4 acc[4];
    #pragma unroll
    for (int ct = 0; ct < 4; ++ct) {
      float bb = bin[ct*16 + p];
      acc[ct] = (f32x4){bb, bb, bb, bb};
    }
    #pragma unroll
    for (int kc = 0; kc < 8; ++kc) {
      float4 xa = *(const float4*)(xrow + kc*32 + g16*8);
      float4 xb = *(const float4*)(xrow + kc*32 + g16*8 + 4);
      bf16x8 af;
      af[0]=(__bf16)xa.x; af[1]=(__bf16)xa.y; af[2]=(__bf16)xa.z; af[3]=(__bf16)xa.w;
      af[4]=(__bf16)xb.x; af[5]=(__bf16)xb.y; af[6]=(__bf16)xb.z; af[7]=(__bf16)xb.w;
      #pragma unroll
      for (int ct = 0; ct < 4; ++ct) {
        bf16x8 bf = *(const bf16x8*)(WinF + (size_t)(kc*4 + ct)*512 + lane*8);
        acc[ct] = __builtin_amdgcn_mfma_f32_16x16x32_bf16(af, bf, acc[ct], 0,0,0);
      }
    }
    #pragma unroll
    for (int r = 0; r < 4; ++r) {
      bf16x4 o;
      o[0] = (__bf16)acc[0][r]; o[1] = (__bf16)acc[1][r];
      o[2] = (__bf16)acc[2][r]; o[3] = (__bf16)acc[3][r];
      *(bf16x4*)(h + (size_t)(row0 + g16*4 + r)*SCC + p*4) = o;
    }
    return;
  }
  // ---- kNN: spatial grid, one wave per query ----
  int q = (bId - 256)*4 + w;           // 0..16383
  int cloud = q >> 13, n = q & 8191;
  float4 qc = coords4[(size_t)cloud*NPTS + n];
  float qx = qc.x, qy = qc.y, qz = qc.z;
  int cx = cell_of(qx), cy = cell_of(qy), cz = cell_of(qz);
  const unsigned int* st = starts + cloud*520;
  const float4* sp = sorted + (size_t)cloud*NPTS;
  int c0 = cx > 0 ? cx-1 : 0;
  int c1 = cx < GD-1 ? cx+1 : GD-1;
  unsigned int cnt = 0;
  for (int dz = -1; dz <= 1; ++dz) {
    int zz = cz + dz; if (zz < 0 || zz > GD-1) continue;
    for (int dy = -1; dy <= 1; ++dy) {
      int yy = cy + dy; if (yy < 0 || yy > GD-1) continue;
      int rb = (zz*GD + yy)*GD;
      unsigned int s = st[rb + c0];
      unsigned int e = st[rb + c1 + 1];
      for (unsigned int jj = s; jj < e; jj += 64) {
        unsigned int j = jj + lane;
        bool keep = false; float d2 = 0.f; unsigned int oi = 0;
        if (j < e) {
          float4 p4 = sp[j];
          float dx = qx-p4.x, dyy = qy-p4.y, dzz = qz-p4.z;
          d2 = fmaf(dx, dx, fmaf(dyy, dyy, dzz*dzz));
          oi = __float_as_uint(p4.w);
          keep = (d2 <= R2F);
        }
        unsigned long long m = __ballot(keep);
        if (keep) {
          unsigned int before = __builtin_amdgcn_mbcnt_hi(
              (unsigned int)(m >> 32),
              __builtin_amdgcn_mbcnt_lo((unsigned int)m, 0u));
          unsigned int pos = cnt + before;
          if (pos < SCAP)
            surv[w][pos] = ((unsigned long long)__float_as_uint(d2) << 32) | oi;
        }
        cnt += (unsigned int)__popcll(m);
      }
    }
  }
  int C = (int)cnt; if (C > SCAP) C = SCAP;
  unsigned long long k0 = (lane      < C) ? surv[w][lane]      : ~0ULL;
  unsigned long long k1 = (lane + 64 < C) ? surv[w][lane + 64] : ~0ULL;
  int r0 = 0, r1 = 0;
  for (int j = 0; j < C; ++j) {
    unsigned long long kj = surv[w][j];      // same addr all lanes: broadcast
    r0 += (kj < k0);
    r1 += (kj < k1);
  }
  size_t g = (size_t)cloud*NPTS + n;
  if (k0 != ~0ULL && r0 < KNN) fidx[g*KNN + r0] = (short)(k0 & 0xffffu);
  if (k1 != ~0ULL && r1 < KNN) fidx[g*KNN + r1] = (short)(k1 & 0xffffu);
  if (lane >= C && lane < KNN) fidx[g*KNN + lane] = (short)-1;   // sentinels
}

// ---- fused KPConv v9: 16 SORTED points/block, 2 pts/wave, full-K Phase B -----
// Points processed in cell-sorted order: a block's 16 points are spatial
// neighbors -> their 32-NN gather sets overlap heavily (hot L1/L2 lines).
// Phase A: wave w does sorted-local points 2w, 2w+1 (32 independent gathers
// in flight -> needs the (512,4) 128-VGPR budget, unlike r11's no-op hint).
// Phase B: waves 0-3, wave=dt, FULL K=960 (30 MFMA), B cols = 16 real points
// (no duplicate-column waste), no cross-wave reduction. h2 written per ORIG
// index (sorted[].w), 256B contiguous per point.
__global__ __launch_bounds__(512, 4) void kpconv_fused(
    const float4* __restrict__ coords4, const float4* __restrict__ sorted,
    const float* __restrict__ kpts, const short* __restrict__ fidx,
    const __bf16* __restrict__ h, const __bf16* __restrict__ WkpT,
    float* __restrict__ h2)
{
  __shared__ __bf16 agg_s[16][AGP2];    // 31.3 KB
  __shared__ float  red2[4*16*17];      // 4.4 KB: [dt][m][pt(17)]
  __shared__ int    oidx_s[16];
  int t = threadIdx.x;
  int w = t >> 6, lane = t & 63;
  int b = blockIdx.x;                   // 1024 blocks: cloud(1)|sg(9)
  int cloud = b >> 9;
  int sbase = (b & 511)*16;             // base in sorted order
  const float4* c4 = coords4 + (size_t)cloud*NPTS;
  const float4* sp = sorted + (size_t)cloud*NPTS;
  int g16 = lane >> 4;                  // k-group: lane covers k=g16*8+j
  int p   = lane & 15;                  // A-row (kernel pt) and B/D column
  int pc  = p < KPN ? p : 0;
  float kpx = kpts[pc*3], kpy = kpts[pc*3+1], kpz = kpts[pc*3+2];
  // ---- Phase A for two points (interleaved for MLP) ----
  bf16x8 afrag[2];
  int idxs[2][8];
  int orig[2];
  #pragma unroll
  for (int hf = 0; hf < 2; ++hf) {
    int lp = w*2 + hf;
    float4 se = sp[sbase + lp];         // wave-uniform broadcast load
    int o = (int)__float_as_uint(se.w);
    orig[hf] = o;
    if (lane == 0) oidx_s[lp] = o;
    int idxreg = fidx[((size_t)cloud*NPTS + o)*KNN + (lane & 31)];
    float qx = se.x, qy = se.y, qz = se.z;
    #pragma unroll
    for (int j = 0; j < 8; ++j) {
      int k = g16*8 + j;
      int idx = __shfl(idxreg, k);
      idxs[hf][j] = idx < 0 ? 0 : idx;
      float4 nc = c4[idxs[hf][j]];      // b128 gather (clamped-safe)
      float wv = 0.f;
      if (idx >= 0 && p < KPN) {
        float dx = (nc.x - qx) - kpx;
        float dy = (nc.y - qy) - kpy;
        float dz = (nc.z - qz) - kpz;
        float d = sqrtf(fmaf(dx, dx, fmaf(dy, dy, dz*dz)));
        wv = fmaxf(1.0f - d*INV_EXT, 0.0f);
      }
      afrag[hf][j] = (__bf16)wv;        // idx<0 -> 0 kills garbage B
    }
  }
  #pragma unroll
  for (int hf = 0; hf < 2; ++hf) {
    bf16x8 bfrag0, bfrag1, bfrag2, bfrag3;
    #pragma unroll
    for (int j = 0; j < 8; ++j) {       // hP[idx][p*4+ct]: one b64 per j
      bf16x4 hv = *(const bf16x4*)(h + ((size_t)cloud*NPTS + idxs[hf][j])*SCC + p*4);
      bfrag0[j] = hv[0]; bfrag1[j] = hv[1]; bfrag2[j] = hv[2]; bfrag3[j] = hv[3];
    }
    f32x4 a0 = {0.f,0.f,0.f,0.f}, a1 = a0, a2 = a0, a3 = a0;
    a0 = __builtin_amdgcn_mfma_f32_16x16x32_bf16(afrag[hf], bfrag0, a0, 0,0,0);
    a1 = __builtin_amdgcn_mfma_f32_16x16x32_bf16(afrag[hf], bfrag1, a1, 0,0,0);
    a2 = __builtin_amdgcn_mfma_f32_16x16x32_bf16(afrag[hf], bfrag2, a2, 0,0,0);
    a3 = __builtin_amdgcn_mfma_f32_16x16x32_bf16(afrag[hf], bfrag3, a3, 0,0,0);
    int lp = w*2 + hf;
    #pragma unroll
    for (int r = 0; r < 4; ++r) {       // D: row pp=g16*4+r, col ct*16+p
      int pp = g16*4 + r;
      if (pp < KPN) {                   // pp==15 is the dummy row
        agg_s[lp][pp*SCC +      p] = (__bf16)a0[r];
        agg_s[lp][pp*SCC + 16 + p] = (__bf16)a1[r];
        agg_s[lp][pp*SCC + 32 + p] = (__bf16)a2[r];
        agg_s[lp][pp*SCC + 48 + p] = (__bf16)a3[r];
      }
    }
  }
  __syncthreads();                      // publish agg_s + oidx_s
  // ---- Phase B: waves 0-3, wave = d-tile, full K=960 (30 MFMA) ----
  if (w < 4) {
    int dt = w;
    const __bf16* arow = WkpT + (size_t)(dt*16 + p)*KJ + g16*8;   // A row m=p
    const __bf16* brow = &agg_s[p][g16*8];                        // B col  =p
    f32x4 accB = {0.f,0.f,0.f,0.f};
    #pragma unroll
    for (int s = 0; s < 30; ++s) {
      bf16x8 af  = *(const bf16x8*)(arow + s*32);
      bf16x8 bfr = *(const bf16x8*)(brow + s*32);
      accB = __builtin_amdgcn_mfma_f32_16x16x32_bf16(af, bfr, accB, 0, 0, 0);
    }
    #pragma unroll
    for (int r = 0; r < 4; ++r)         // D row m=g16*4+r, col pt=p
      red2[(dt*16 + g16*4 + r)*17 + p] = accB[r];
  }
  __syncthreads();                      // publish red2
  #pragma unroll
  for (int e = t; e < 1024; e += 512) { // 16 pts x 64 d
    int pt = e >> 6, d = e & 63;
    float v = red2[((d >> 4)*16 + (d & 15))*17 + pt];
    h2[((size_t)cloud*NPTS + oidx_s[pt])*SCC + d] = v;
  }
}

// ---- conv_out + bias + BN partial stats: tiled GEMM, all operands in LDS -----
__global__ __launch_bounds__(512) void conv_out_bn(
    const float* __restrict__ h2, const float* __restrict__ W,
    const float* __restrict__ b, float* __restrict__ y,
    float* __restrict__ stats)
{
  __shared__ float w_s[SCC*OUTC];      // 64 KB
  __shared__ float h_s[COB][SCC];      // 8 KB
  __shared__ float rs_s[2][OUTC];      // 2 KB
  __shared__ float rs2_s[2][OUTC];     // 2 KB
  int t = threadIdx.x;
  int d = t & 255, rg = t >> 8;        // rg in {0,1}: 16-row halves
  int row0 = blockIdx.x*COB;
  int cloud = (int)(blockIdx.x >> 8);  // 256 blocks per cloud
  {
    const float4* gw = (const float4*)W;
    float4* lw = (float4*)w_s;
    #pragma unroll
    for (int i = 0; i < 8; ++i) lw[t + 512*i] = gw[t + 512*i];
    const float4* gh = (const float4*)(h2 + (size_t)row0*SCC);
    ((float4*)h_s)[t] = gh[t];
  }
  __syncthreads();
  float acc[16];
  float bb = b[d];
  #pragma unroll
  for (int r = 0; r < 16; ++r) acc[r] = bb;
  int rb = rg*16;
  #pragma unroll 4
  for (int c4 = 0; c4 < 16; ++c4) {
    float w0 = w_s[(c4*4+0)*OUTC + d];
    float w1 = w_s[(c4*4+1)*OUTC + d];
    float w2 = w_s[(c4*4+2)*OUTC + d];
    float w3 = w_s[(c4*4+3)*OUTC + d];
    #pragma unroll
    for (int r = 0; r < 16; ++r) {
      float4 hv = *(const float4*)&h_s[rb + r][c4*4];
      acc[r] = fmaf(hv.x,w0, fmaf(hv.y,w1, fmaf(hv.z,w2, fmaf(hv.w,w3, acc[r]))));
    }
  }
  float s = 0.f, s2 = 0.f;
  #pragma unroll
  for (int r = 0; r < 16; ++r) {
    float v = acc[r];
    y[((size_t)row0 + rb + r)*OUTC + d] = v;
    s += v; s2 = fmaf(v, v, s2);
  }
  rs_s[rg][d] = s; rs2_s[rg][d] = s2;
  __syncthreads();
  if (rg == 0) {
    atomicAdd(&stats[cloud*512 + d],       s  + rs_s[1][d]);
    atomicAdd(&stats[cloud*512 + 256 + d], s2 + rs2_s[1][d]);
  }
}

// ---- BN apply ----------------------------------------------------------------
__global__ __launch_bounds__(256) void bn_apply_k(
    float* __restrict__ y, const float* __restrict__ stats,
    const float* __restrict__ gamma, const float* __restrict__ beta)
{
  size_t e = (size_t)blockIdx.x*256 + threadIdx.x;
  int c = (int)(e & 255);
  int cloud = (int)(e >> 21);
  float s  = stats[cloud*512 + c];
  float s2 = stats[cloud*512 + 256 + c];
  float mu  = s * (1.0f/NPTS);
  float var = fmaxf(s2 * (1.0f/NPTS) - mu*mu, 0.f);
  float sc = gamma[c] * rsqrtf(var + 1e-5f);
  float sh = beta[c] - mu*sc;
  float v = fmaf(y[e], sc, sh);
  v = v > 0.f ? v : 0.1f*v;
  y[e] = v;
}

extern "C" void kernel_launch(void* const* d_in, const int* in_sizes, int n_in,
                              void* d_out, int out_size, void* d_ws, size_t ws_size,
                              hipStream_t stream)
{
  (void)in_sizes; (void)n_in; (void)out_size; (void)ws_size;
  const float* src   = (const float*)d_in[0];
  const float* tgt   = (const float*)d_in[1];
  const float* scd   = (const float*)d_in[2];
  const float* tcd   = (const float*)d_in[3];
  const float* W_in  = (const float*)d_in[4];
  const float* b_in  = (const float*)d_in[5];
  const float* kpts  = (const float*)d_in[6];
  const float* W_kp  = (const float*)d_in[7];
  const float* W_out = (const float*)d_in[8];
  const float* b_out = (const float*)d_in[9];
  const float* gamma = (const float*)d_in[10];
  const float* beta  = (const float*)d_in[11];

  // ---- workspace (~10.6 MB; sorted/starts/cursor moved OUT of the h2
  // region: kpconv v9 reads sorted while writing h2) ----
  char* ws = (char*)d_ws;
  __bf16* h    = (__bf16*)ws;                       // 0..2 MB  hP[2*8192][64] bf16
  float* h2    = (float*)(ws + (4u<<20));           // 4..8 MB  [2][8192][64] f32
  short* fidx  = (short*)(ws + (8u<<20));           // 8..9 MB [16384][32] i16
  float* stats = (float*)(ws + (9u<<20));           // 4 KB
  __bf16* WkpT = (__bf16*)(ws + (9u<<20) + (64u<<10));   // 120 KB [64][960] bf16
  __bf16* WinF = (__bf16*)(ws + (9u<<20) + (256u<<10));  // 32 KB fragment-ordered
  float4* coords4 = (float4*)(ws + (9u<<20) + (512u<<10)); // 256 KB [2][8192]
  float4* sorted  = (float4*)(ws + (10u<<20));             // 256 KB [2][8192]
  unsigned int* starts = (unsigned int*)(ws + (10u<<20) + (512u<<10)); // 4.2 KB
  unsigned int* cursor = (unsigned int*)(ws + (10u<<20) + (520u<<10)); // 4 KB

  float* yout = (float*)d_out;

  prep_k<<<496, 256, 0, stream>>>(scd, tcd, yout + (size_t)2*NPTS*OUTC,
                                  W_kp, WkpT, W_in, WinF);
  grid_build<<<1, 1024, 0, stream>>>(scd, tcd, starts, cursor, stats);
  grid_scatter<<<64, 256, 0, stream>>>(scd, tcd, cursor, sorted, coords4);
  knn_convin_k<<<4352, 256, 0, stream>>>(coords4, starts, sorted, fidx,
                                         src, tgt, WinF, b_in, h);
  kpconv_fused<<<1024, 512, 0, stream>>>(coords4, sorted, kpts, fidx, h, WkpT, h2);
  conv_out_bn<<<512, 512, 0, stream>>>(h2, W_out, b_out, yout, stats);
  bn_apply_k<<<16384, 256, 0, stream>>>(yout, stats, gamma, beta);
}

// Round 14
// 174.640 us; speedup vs baseline: 1.1679x; 1.1215x over previous
//
#include <hip/hip_runtime.h>
#include <stdint.h>

#define NPTS 8192
#define KNN 32
#define KPN 15
#define SCC 64
#define OUTC 256
#define R2F 0.0144f              /* radius^2: the reference's in_range mask.
                                    NOTE: must be RADIUS^2, NOT EXTENT^2 —
                                    influence is dist(rel, kernel_pt) < EXT,
                                    and kernel points are offset from origin,
                                    so neighbors in (EXT, RADIUS] contribute. */
#define INV_EXT (1.0f/0.096f)
#define SCAP 128                 /* per-query survivor cap */
#define GD 8                     /* grid dim: cell 0.125 >= RADIUS 0.12 */
#define NCELL (GD*GD*GD)         /* 512 cells per cloud */
#define KJ (KPN*SCC)             /* 960: contraction length */
#define AGP2 1000                /* agg_s row stride (bf16) */

typedef float  f32x4  __attribute__((ext_vector_type(4)));
typedef __bf16 bf16x8 __attribute__((ext_vector_type(8)));
typedef __bf16 bf16x4 __attribute__((ext_vector_type(4)));

__device__ __forceinline__ int cell_of(float x) {
  int c = (int)(x * (float)GD);
  return c < 0 ? 0 : (c > GD-1 ? GD-1 : c);
}

// ---- prep v2 (1024-thr blocks): coords | WkpT | WinF | WoutF | grid-build ---
// blocks 0..47: coords copy; 48..107: WkpT; 108..123: WinF; 124..155: WoutF;
// block 156: grid histogram+scan+stats-zero (serial block overlaps the rest).
__global__ __launch_bounds__(1024) void prep_k(
    const float* __restrict__ scd, const float* __restrict__ tcd,
    float* __restrict__ out,
    const float* __restrict__ Wkp, __bf16* __restrict__ WkpT,
    const float* __restrict__ Win, __bf16* __restrict__ WinF,
    const float* __restrict__ Wout, __bf16* __restrict__ WoutF,
    unsigned int* __restrict__ starts, unsigned int* __restrict__ cursor,
    float* __restrict__ stats)
{
  __shared__ unsigned int hcnt[2][NCELL];  // grid-build scratch (block 156)
  __shared__ unsigned int sa[NCELL], sb[NCELL];
  int b = blockIdx.x, t = threadIdx.x;
  if (b < 48) {                        // coords: 49152 floats
    int i = b*1024 + t;
    out[i] = (i < NPTS*3) ? scd[i] : tcd[i - NPTS*3];
  } else if (b < 108) {                // WkpT[d][j] = Wkp[j][d], bf16
    int i = (b - 48)*1024 + t;         // 0..61439
    int j = i >> 6, d = i & 63;
    WkpT[(size_t)d*KJ + j] = (__bf16)Wkp[i];
  } else if (b < 124) {                // WinF fragment-ordered bf16 (32 KB)
    int i = (b - 108)*1024 + t;        // 0..16383
    int j = i & 7, lane = (i >> 3) & 63, cc = i >> 9;   // cc = kc*4+ct
    int kc = cc >> 2, ct = cc & 3;
    int g16 = lane >> 4, p = lane & 15;
    int k = kc*32 + g16*8 + j;
    WinF[i] = (__bf16)Win[(size_t)k*64 + ct*16 + p];
  } else if (b < 156) {                // WoutF fragment-ordered bf16 (32 KB)
    int i = (b - 124)*1024 + t;        // 0..32767
    int j = i & 7, lane = (i >> 3) & 63, cc = i >> 9;   // cc = kc*16+ct
    int kc = cc >> 4, ct = cc & 15;
    int g16 = lane >> 4, p = lane & 15;
    int k = kc*32 + g16*8 + j;
    WoutF[i] = (__bf16)Wout[(size_t)k*256 + ct*16 + p];
  } else {                             // grid build + stats zero (1 block)
    if (t < NCELL) { hcnt[0][t] = 0u; hcnt[1][t] = 0u; }
    stats[t] = 0.f;                    // 1024 = 2 clouds x 512
    __syncthreads();
    for (int i = t; i < 2*NPTS; i += 1024) {
      int cloud = i >> 13, n = i & 8191;
      const float* coords = cloud ? tcd : scd;
      int cx = cell_of(coords[(size_t)n*3]);
      int cy = cell_of(coords[(size_t)n*3+1]);
      int cz = cell_of(coords[(size_t)n*3+2]);
      atomicAdd(&hcnt[cloud][(cz*GD + cy)*GD + cx], 1u);
    }
    __syncthreads();
    for (int cloud = 0; cloud < 2; ++cloud) {
      if (t < NCELL) sa[t] = hcnt[cloud][t];
      __syncthreads();
      unsigned int *s = sa, *d = sb;
      for (int off = 1; off < NCELL; off <<= 1) {
        if (t < NCELL) {
          unsigned int x = s[t];
          if (t >= off) x += s[t - off];
          d[t] = x;
        }
        __syncthreads();
        unsigned int* tmp = s; s = d; d = tmp;
      }
      if (t < NCELL) {
        unsigned int inc = s[t];
        unsigned int exc = inc - hcnt[cloud][t];
        starts[cloud*520 + t] = exc;
        cursor[cloud*NCELL + t] = exc;
        if (t == NCELL-1) starts[cloud*520 + NCELL] = inc;   // = 8192
      }
      __syncthreads();
    }
  }
}

// ---- scatter: cell-sorted float4 + dense coords4 gather table ---------------
__global__ __launch_bounds__(256) void grid_scatter(
    const float* __restrict__ cA, const float* __restrict__ cB,
    unsigned int* __restrict__ cursor, float4* __restrict__ sorted,
    float4* __restrict__ coords4)
{
  int i = blockIdx.x*256 + threadIdx.x;   // 0..16383
  int cloud = i >> 13, n = i & 8191;
  const float* coords = cloud ? cB : cA;
  float x = coords[(size_t)n*3], y = coords[(size_t)n*3+1], z = coords[(size_t)n*3+2];
  coords4[(size_t)cloud*NPTS + n] = make_float4(x, y, z, 0.f);
  int cell = (cell_of(z)*GD + cell_of(y))*GD + cell_of(x);
  unsigned int slot = atomicAdd(&cursor[cloud*NCELL + cell], 1u);
  sorted[(size_t)cloud*NPTS + slot] = make_float4(x, y, z, __int_as_float(n));
}

// ---- conv_in MFMA (blocks 0..255, FIRST: HBM loads overlap knn) + kNN -------
__global__ __launch_bounds__(256) void knn_convin_k(
    const float4* __restrict__ coords4,
    const unsigned int* __restrict__ starts, const float4* __restrict__ sorted,
    short* __restrict__ fidx,
    const float* __restrict__ src, const float* __restrict__ tgt,
    const __bf16* __restrict__ WinF, const float* __restrict__ bin,
    __bf16* __restrict__ h)
{
  __shared__ unsigned long long surv[4][SCAP];   // 4 KB, wave-private rows
  int bId = blockIdx.x;
  int t = threadIdx.x, w = t >> 6, lane = t & 63;
  if (bId < 256) {
    // conv_in: afrag=A[m=lane&15][kslot], bfrag=B[kslot][n=lane&15],
    // D col=lane&15 row=(lane>>4)*4+r (HW-verified). hP output layout:
    // hP[n][p*4+ct] = h[n][ct*16+p] -> one b64 store per row.
    int rt = bId*4 + w;                // row-tile 0..1023
    int row0 = rt*16;
    const float* x = (row0 >> 13) ? tgt : src;
    int n0 = row0 & 8191;
    int g16 = lane >> 4, p = lane & 15;
    const float* xrow = x + (size_t)(n0 + p)*256;
    f32x4 acc[4];
    #pragma unroll
    for (int ct = 0; ct < 4; ++ct) {
      float bb = bin[ct*16 + p];
      acc[ct] = (f32x4){bb, bb, bb, bb};
    }
    #pragma unroll
    for (int kc = 0; kc < 8; ++kc) {
      float4 xa = *(const float4*)(xrow + kc*32 + g16*8);
      float4 xb = *(const float4*)(xrow + kc*32 + g16*8 + 4);
      bf16x8 af;
      af[0]=(__bf16)xa.x; af[1]=(__bf16)xa.y; af[2]=(__bf16)xa.z; af[3]=(__bf16)xa.w;
      af[4]=(__bf16)xb.x; af[5]=(__bf16)xb.y; af[6]=(__bf16)xb.z; af[7]=(__bf16)xb.w;
      #pragma unroll
      for (int ct = 0; ct < 4; ++ct) {
        bf16x8 bf = *(const bf16x8*)(WinF + (size_t)(kc*4 + ct)*512 + lane*8);
        acc[ct] = __builtin_amdgcn_mfma_f32_16x16x32_bf16(af, bf, acc[ct], 0,0,0);
      }
    }
    #pragma unroll
    for (int r = 0; r < 4; ++r) {
      bf16x4 o;
      o[0] = (__bf16)acc[0][r]; o[1] = (__bf16)acc[1][r];
      o[2] = (__bf16)acc[2][r]; o[3] = (__bf16)acc[3][r];
      *(bf16x4*)(h + (size_t)(row0 + g16*4 + r)*SCC + p*4) = o;
    }
    return;
  }
  // ---- kNN: spatial grid, one wave per query ----
  int q = (bId - 256)*4 + w;           // 0..16383
  int cloud = q >> 13, n = q & 8191;
  float4 qc = coords4[(size_t)cloud*NPTS + n];
  float qx = qc.x, qy = qc.y, qz = qc.z;
  int cx = cell_of(qx), cy = cell_of(qy), cz = cell_of(qz);
  const unsigned int* st = starts + cloud*520;
  const float4* sp = sorted + (size_t)cloud*NPTS;
  int c0 = cx > 0 ? cx-1 : 0;
  int c1 = cx < GD-1 ? cx+1 : GD-1;
  unsigned int cnt = 0;
  for (int dz = -1; dz <= 1; ++dz) {
    int zz = cz + dz; if (zz < 0 || zz > GD-1) continue;
    for (int dy = -1; dy <= 1; ++dy) {
      int yy = cy + dy; if (yy < 0 || yy > GD-1) continue;
      int rb = (zz*GD + yy)*GD;
      unsigned int s = st[rb + c0];
      unsigned int e = st[rb + c1 + 1];
      for (unsigned int jj = s; jj < e; jj += 64) {
        unsigned int j = jj + lane;
        bool keep = false; float d2 = 0.f; unsigned int oi = 0;
        if (j < e) {
          float4 p4 = sp[j];
          float dx = qx-p4.x, dyy = qy-p4.y, dzz = qz-p4.z;
          d2 = fmaf(dx, dx, fmaf(dyy, dyy, dzz*dzz));
          oi = __float_as_uint(p4.w);
          keep = (d2 <= R2F);
        }
        unsigned long long m = __ballot(keep);
        if (keep) {
          unsigned int before = __builtin_amdgcn_mbcnt_hi(
              (unsigned int)(m >> 32),
              __builtin_amdgcn_mbcnt_lo((unsigned int)m, 0u));
          unsigned int pos = cnt + before;
          if (pos < SCAP)
            surv[w][pos] = ((unsigned long long)__float_as_uint(d2) << 32) | oi;
        }
        cnt += (unsigned int)__popcll(m);
      }
    }
  }
  int C = (int)cnt; if (C > SCAP) C = SCAP;
  unsigned long long k0 = (lane      < C) ? surv[w][lane]      : ~0ULL;
  unsigned long long k1 = (lane + 64 < C) ? surv[w][lane + 64] : ~0ULL;
  int r0 = 0, r1 = 0;
  for (int j = 0; j < C; ++j) {
    unsigned long long kj = surv[w][j];      // same addr all lanes: broadcast
    r0 += (kj < k0);
    r1 += (kj < k1);
  }
  size_t g = (size_t)cloud*NPTS + n;
  if (k0 != ~0ULL && r0 < KNN) fidx[g*KNN + r0] = (short)(k0 & 0xffffu);
  if (k1 != ~0ULL && r1 < KNN) fidx[g*KNN + r1] = (short)(k1 & 0xffffu);
  if (lane >= C && lane < KNN) fidx[g*KNN + lane] = (short)-1;   // sentinels
}

// ---- fused KPConv v10: 16 sorted pts/block, bf16 h2 output -------------------
__global__ __launch_bounds__(512, 4) void kpconv_fused(
    const float4* __restrict__ coords4, const float4* __restrict__ sorted,
    const float* __restrict__ kpts, const short* __restrict__ fidx,
    const __bf16* __restrict__ h, const __bf16* __restrict__ WkpT,
    __bf16* __restrict__ h2)
{
  __shared__ __bf16 agg_s[16][AGP2];    // 31.3 KB
  __shared__ float  red2[4*16*17];      // 4.4 KB: [dt][m][pt(17)]
  __shared__ int    oidx_s[16];
  int t = threadIdx.x;
  int w = t >> 6, lane = t & 63;
  int b = blockIdx.x;                   // 1024 blocks: cloud(1)|sg(9)
  int cloud = b >> 9;
  int sbase = (b & 511)*16;             // base in sorted order
  const float4* c4 = coords4 + (size_t)cloud*NPTS;
  const float4* sp = sorted + (size_t)cloud*NPTS;
  int g16 = lane >> 4;                  // k-group: lane covers k=g16*8+j
  int p   = lane & 15;                  // A-row (kernel pt) and B/D column
  int pc  = p < KPN ? p : 0;
  float kpx = kpts[pc*3], kpy = kpts[pc*3+1], kpz = kpts[pc*3+2];
  // ---- Phase A for two points (interleaved for MLP) ----
  bf16x8 afrag[2];
  int idxs[2][8];
  #pragma unroll
  for (int hf = 0; hf < 2; ++hf) {
    int lp = w*2 + hf;
    float4 se = sp[sbase + lp];         // wave-uniform broadcast load
    int o = (int)__float_as_uint(se.w);
    if (lane == 0) oidx_s[lp] = o;
    int idxreg = fidx[((size_t)cloud*NPTS + o)*KNN + (lane & 31)];
    float qx = se.x, qy = se.y, qz = se.z;
    #pragma unroll
    for (int j = 0; j < 8; ++j) {
      int k = g16*8 + j;
      int idx = __shfl(idxreg, k);
      idxs[hf][j] = idx < 0 ? 0 : idx;
      float4 nc = c4[idxs[hf][j]];      // b128 gather (clamped-safe)
      float wv = 0.f;
      if (idx >= 0 && p < KPN) {
        float dx = (nc.x - qx) - kpx;
        float dy = (nc.y - qy) - kpy;
        float dz = (nc.z - qz) - kpz;
        float d = sqrtf(fmaf(dx, dx, fmaf(dy, dy, dz*dz)));
        wv = fmaxf(1.0f - d*INV_EXT, 0.0f);
      }
      afrag[hf][j] = (__bf16)wv;        // idx<0 -> 0 kills garbage B
    }
  }
  #pragma unroll
  for (int hf = 0; hf < 2; ++hf) {
    bf16x8 bfrag0, bfrag1, bfrag2, bfrag3;
    #pragma unroll
    for (int j = 0; j < 8; ++j) {       // hP[idx][p*4+ct]: one b64 per j
      bf16x4 hv = *(const bf16x4*)(h + ((size_t)cloud*NPTS + idxs[hf][j])*SCC + p*4);
      bfrag0[j] = hv[0]; bfrag1[j] = hv[1]; bfrag2[j] = hv[2]; bfrag3[j] = hv[3];
    }
    f32x4 a0 = {0.f,0.f,0.f,0.f}, a1 = a0, a2 = a0, a3 = a0;
    a0 = __builtin_amdgcn_mfma_f32_16x16x32_bf16(afrag[hf], bfrag0, a0, 0,0,0);
    a1 = __builtin_amdgcn_mfma_f32_16x16x32_bf16(afrag[hf], bfrag1, a1, 0,0,0);
    a2 = __builtin_amdgcn_mfma_f32_16x16x32_bf16(afrag[hf], bfrag2, a2, 0,0,0);
    a3 = __builtin_amdgcn_mfma_f32_16x16x32_bf16(afrag[hf], bfrag3, a3, 0,0,0);
    int lp = w*2 + hf;
    #pragma unroll
    for (int r = 0; r < 4; ++r) {       // D: row pp=g16*4+r, col ct*16+p
      int pp = g16*4 + r;
      if (pp < KPN) {                   // pp==15 is the dummy row
        agg_s[lp][pp*SCC +      p] = (__bf16)a0[r];
        agg_s[lp][pp*SCC + 16 + p] = (__bf16)a1[r];
        agg_s[lp][pp*SCC + 32 + p] = (__bf16)a2[r];
        agg_s[lp][pp*SCC + 48 + p] = (__bf16)a3[r];
      }
    }
  }
  __syncthreads();                      // publish agg_s + oidx_s
  // ---- Phase B: waves 0-3, wave = d-tile, full K=960 (30 MFMA) ----
  if (w < 4) {
    int dt = w;
    const __bf16* arow = WkpT + (size_t)(dt*16 + p)*KJ + g16*8;   // A row m=p
    const __bf16* brow = &agg_s[p][g16*8];                        // B col  =p
    f32x4 accB = {0.f,0.f,0.f,0.f};
    #pragma unroll
    for (int s = 0; s < 30; ++s) {
      bf16x8 af  = *(const bf16x8*)(arow + s*32);
      bf16x8 bfr = *(const bf16x8*)(brow + s*32);
      accB = __builtin_amdgcn_mfma_f32_16x16x32_bf16(af, bfr, accB, 0, 0, 0);
    }
    #pragma unroll
    for (int r = 0; r < 4; ++r)         // D row m=g16*4+r, col pt=p
      red2[(dt*16 + g16*4 + r)*17 + p] = accB[r];
  }
  __syncthreads();                      // publish red2
  #pragma unroll
  for (int e = t; e < 1024; e += 512) { // 16 pts x 64 d, bf16 out
    int pt = e >> 6, d = e & 63;
    float v = red2[((d >> 4)*16 + (d & 15))*17 + pt];
    h2[((size_t)cloud*NPTS + oidx_s[pt])*SCC + d] = (__bf16)v;
  }
}

// ---- conv_out v2: MFMA GEMM [16384x64]@[64x256] + bias + BN partials --------
// Same fragment contract as conv_in. A = h2 bf16 rows (b128 loads);
// B = WoutF fragment-ordered (L2-hot, 32KB). 16 rows/wave, 32 MFMA.
// Stats: shfl-reduce over g16 -> LDS per-wave slabs -> 1 atomic/(block,col).
__global__ __launch_bounds__(256, 2) void conv_out_bn(
    const __bf16* __restrict__ h2, const __bf16* __restrict__ WoutF,
    const float* __restrict__ b, float* __restrict__ y,
    float* __restrict__ stats)
{
  __shared__ float rs_s[4][OUTC];      // 4 KB
  __shared__ float rs2_s[4][OUTC];     // 4 KB
  int t = threadIdx.x, w = t >> 6, lane = t & 63;
  int g16 = lane >> 4, p = lane & 15;
  int rt = blockIdx.x*4 + w;           // row-tile 0..1023
  int row0 = rt*16;
  int cloud = blockIdx.x >> 7;         // 64 rows/block, 128 blocks/cloud
  const __bf16* arow = h2 + (size_t)(row0 + p)*SCC;   // this lane's A-row
  f32x4 acc[16];
  #pragma unroll
  for (int ct = 0; ct < 16; ++ct) {
    float bb = b[ct*16 + p];
    acc[ct] = (f32x4){bb, bb, bb, bb};
  }
  #pragma unroll
  for (int kc = 0; kc < 2; ++kc) {
    bf16x8 af = *(const bf16x8*)(arow + kc*32 + g16*8);
    #pragma unroll
    for (int ct = 0; ct < 16; ++ct) {
      bf16x8 bf = *(const bf16x8*)(WoutF + (size_t)(kc*16 + ct)*512 + lane*8);
      acc[ct] = __builtin_amdgcn_mfma_f32_16x16x32_bf16(af, bf, acc[ct], 0,0,0);
    }
  }
  #pragma unroll
  for (int ct = 0; ct < 16; ++ct) {
    float s = 0.f, s2 = 0.f;
    #pragma unroll
    for (int r = 0; r < 4; ++r) {      // D row m=g16*4+r, col ct*16+p
      float v = acc[ct][r];
      y[((size_t)row0 + g16*4 + r)*OUTC + ct*16 + p] = v;
      s += v; s2 = fmaf(v, v, s2);
    }
    s  += __shfl_xor(s, 16);  s  += __shfl_xor(s, 32);
    s2 += __shfl_xor(s2, 16); s2 += __shfl_xor(s2, 32);
    if (g16 == 0) { rs_s[w][ct*16 + p] = s; rs2_s[w][ct*16 + p] = s2; }
  }
  __syncthreads();
  if (t < 256) {
    float S  = rs_s[0][t]  + rs_s[1][t]  + rs_s[2][t]  + rs_s[3][t];
    float S2 = rs2_s[0][t] + rs2_s[1][t] + rs2_s[2][t] + rs2_s[3][t];
    atomicAdd(&stats[cloud*512 + t],       S);
    atomicAdd(&stats[cloud*512 + 256 + t], S2);
  }
}

// ---- BN apply: float4 vectorized ---------------------------------------------
__global__ __launch_bounds__(256) void bn_apply_k(
    float* __restrict__ y, const float* __restrict__ stats,
    const float* __restrict__ gamma, const float* __restrict__ beta)
{
  size_t i = (size_t)blockIdx.x*256 + threadIdx.x;
  size_t e4 = i*4;                     // < 2*8192*256
  int c0 = (int)(e4 & 255);
  int cloud = (int)(e4 >> 21);
  float4 v = *(float4*)&y[e4];
  float vv[4] = {v.x, v.y, v.z, v.w};
  #pragma unroll
  for (int k = 0; k < 4; ++k) {
    int c = c0 + k;
    float s  = stats[cloud*512 + c];
    float s2 = stats[cloud*512 + 256 + c];
    float mu  = s * (1.0f/NPTS);
    float var = fmaxf(s2 * (1.0f/NPTS) - mu*mu, 0.f);
    float sc = gamma[c] * rsqrtf(var + 1e-5f);
    float sh = beta[c] - mu*sc;
    float o = fmaf(vv[k], sc, sh);
    vv[k] = o > 0.f ? o : 0.1f*o;
  }
  *(float4*)&y[e4] = make_float4(vv[0], vv[1], vv[2], vv[3]);
}

extern "C" void kernel_launch(void* const* d_in, const int* in_sizes, int n_in,
                              void* d_out, int out_size, void* d_ws, size_t ws_size,
                              hipStream_t stream)
{
  (void)in_sizes; (void)n_in; (void)out_size; (void)ws_size;
  const float* src   = (const float*)d_in[0];
  const float* tgt   = (const float*)d_in[1];
  const float* scd   = (const float*)d_in[2];
  const float* tcd   = (const float*)d_in[3];
  const float* W_in  = (const float*)d_in[4];
  const float* b_in  = (const float*)d_in[5];
  const float* kpts  = (const float*)d_in[6];
  const float* W_kp  = (const float*)d_in[7];
  const float* W_out = (const float*)d_in[8];
  const float* b_out = (const float*)d_in[9];
  const float* gamma = (const float*)d_in[10];
  const float* beta  = (const float*)d_in[11];

  // ---- workspace (~10.6 MB) ----
  char* ws = (char*)d_ws;
  __bf16* h    = (__bf16*)ws;                       // 0..2 MB  hP[2*8192][64] bf16
  __bf16* h2   = (__bf16*)(ws + (4u<<20));          // 2 MB [2][8192][64] bf16
  short* fidx  = (short*)(ws + (8u<<20));           // 8..9 MB [16384][32] i16
  float* stats = (float*)(ws + (9u<<20));           // 4 KB
  __bf16* WkpT = (__bf16*)(ws + (9u<<20) + (64u<<10));   // 120 KB [64][960] bf16
  __bf16* WinF = (__bf16*)(ws + (9u<<20) + (256u<<10));  // 32 KB fragment-ordered
  __bf16* WoutF = (__bf16*)(ws + (9u<<20) + (320u<<10)); // 32 KB fragment-ordered
  float4* coords4 = (float4*)(ws + (9u<<20) + (512u<<10)); // 256 KB [2][8192]
  float4* sorted  = (float4*)(ws + (10u<<20));             // 256 KB [2][8192]
  unsigned int* starts = (unsigned int*)(ws + (10u<<20) + (512u<<10)); // 4.2 KB
  unsigned int* cursor = (unsigned int*)(ws + (10u<<20) + (520u<<10)); // 4 KB

  float* yout = (float*)d_out;

  prep_k<<<157, 1024, 0, stream>>>(scd, tcd, yout + (size_t)2*NPTS*OUTC,
                                   W_kp, WkpT, W_in, WinF, W_out, WoutF,
                                   starts, cursor, stats);
  grid_scatter<<<64, 256, 0, stream>>>(scd, tcd, cursor, sorted, coords4);
  knn_convin_k<<<4352, 256, 0, stream>>>(coords4, starts, sorted, fidx,
                                         src, tgt, WinF, b_in, h);
  kpconv_fused<<<1024, 512, 0, stream>>>(coords4, sorted, kpts, fidx, h, WkpT, h2);
  conv_out_bn<<<256, 256, 0, stream>>>(h2, WoutF, b_out, yout, stats);
  bn_apply_k<<<4096, 256, 0, stream>>>(yout, stats, gamma, beta);
}